// Round 2
// baseline (400.514 us; speedup 1.0000x reference)
//
#include <hip/hip_runtime.h>

typedef _Float16 f16;
typedef _Float16 f16x4 __attribute__((ext_vector_type(4)));
typedef _Float16 f16x8 __attribute__((ext_vector_type(8)));
typedef float    f32x4 __attribute__((ext_vector_type(4)));

#define DEV static __device__ __forceinline__

DEV f32x4 mfma16(f16x8 a, f16x8 b, f32x4 c) {
    return __builtin_amdgcn_mfma_f32_16x16x32_f16(a, b, c, 0, 0, 0);
}

// async global->LDS, 16B per lane, dest = wave-uniform base + lane*16
DEV void gload16(const f16* g, f16* l) {
    __builtin_amdgcn_global_load_lds(
        (const __attribute__((address_space(1))) unsigned int*)g,
        (__attribute__((address_space(3))) unsigned int*)l,
        16, 0, 0);
}

// ---------------------------------------------------------------- constants
// B=4, S=1024, D=768, H=12, DH=64, R=129 (padded to 160 for k-steps of 32)

// ---------------------------------------------------------------- convert (+embVt fold)
struct ConvArgs {
    const float* src[8];
    f16*         dst[8];
};

__global__ __launch_bounds__(256) void k_convert(ConvArgs a,
                                                 const float* __restrict__ embV,
                                                 f16* __restrict__ embVtd) {
    const int bx = blockIdx.x;
    if (bx >= 2048) {  // embVt tail blocks: embVt[h][dh][r] transpose+pad
        const int idx = (bx - 2048) * 256 + threadIdx.x;
        if (idx >= 12 * 64 * 160) return;
        const int r  = idx % 160;
        const int dh = (idx / 160) % 64;
        const int h  = idx / (160 * 64);
        float v = 0.f;
        if (r < 129) v = embV[r * 768 + h * 64 + dh];
        embVtd[idx] = (f16)v;
        return;
    }
    const int seg[9] = {0, 786432, 1572864, 2359296, 2506752, 2654208,
                        2801664, 2949120, 2973888};
    for (int i = bx * 256 + threadIdx.x; i < 2973888; i += 2048 * 256) {
        int s = 0;
        while (i >= seg[s + 1]) s++;
        const int j = i - seg[s];
        const float4 v = ((const float4*)a.src[s])[j];
        f16x4 o;
        o[0] = (f16)v.x; o[1] = (f16)v.y; o[2] = (f16)v.z; o[3] = (f16)v.w;
        ((f16x4*)a.dst[s])[j] = o;
    }
}

// ---------------------------------------------------------------- GEMM core
// 128x128 tile, BK=32, DOUBLE-BUFFERED 2-phase pipeline (T3-minimum):
// issue STAGE(next) before computing current; counted s_waitcnt vmcnt(4)
// + raw s_barrier (NOT __syncthreads: that drains vmcnt(0) and kills the
// pipeline). lgkmcnt(0)+barrier after compute protects the buffer that
// the next iteration's STAGE overwrites. XOR chunk swizzle as before:
// slot (r,c) holds global chunk c^s(r), s(r)=((r)^(r>>2))&3.
// NOTE: all macro locals must avoid kernel-parameter names (xq bug, round 2).
#define GEMM_TILE_BODY(X, W)                                                   \
    const int tid = threadIdx.x;                                               \
    const int w = tid >> 6, l = tid & 63, quad = l >> 4, l16 = l & 15;         \
    const int wr = w >> 1, wc = w & 1;                                         \
    const int rl = l >> 2, cc = l & 3;                                         \
    const int csrc = (cc ^ ((rl ^ (rl >> 2)) & 3)) * 8;                        \
    const f16* gA = (X) + (size_t)(m0 + w * 32 + rl) * 768 + csrc;             \
    const f16* gB = (W) + (size_t)(n0 + w * 32 + rl) * 768 + csrc;             \
    const int xsw = (quad ^ ((l16 ^ (l16 >> 2)) & 3)) * 8;                     \
    f32x4 acc[4][4] = {};                                                      \
    auto STAGE = [&](int pp, int kk) {                                         \
        f16* lA = As + pp * 4096 + (w * 32) * 32;                              \
        f16* lB = Bs + pp * 4096 + (w * 32) * 32;                              \
        gload16(gA + kk, lA);                                                  \
        gload16(gA + kk + 16 * 768, lA + 16 * 32);                             \
        gload16(gB + kk, lB);                                                  \
        gload16(gB + kk + 16 * 768, lB + 16 * 32);                             \
    };                                                                         \
    auto COMPUTE = [&](int pp) {                                               \
        const f16* Ab = As + pp * 4096;                                        \
        const f16* Bb = Bs + pp * 4096;                                        \
        f16x8 af[4], bf[4];                                                    \
        _Pragma("unroll") for (int i = 0; i < 4; i++)                          \
            af[i] = *(const f16x8*)(Ab + (wr * 64 + i * 16 + l16) * 32 + xsw); \
        _Pragma("unroll") for (int i = 0; i < 4; i++)                          \
            bf[i] = *(const f16x8*)(Bb + (wc * 64 + i * 16 + l16) * 32 + xsw); \
        _Pragma("unroll") for (int i = 0; i < 4; i++)                          \
            _Pragma("unroll") for (int j = 0; j < 4; j++)                      \
                acc[i][j] = mfma16(af[i], bf[j], acc[i][j]);                   \
    };                                                                         \
    STAGE(0, 0);                                                               \
    _Pragma("unroll 1") for (int t = 0; t < 23; ++t) {                         \
        STAGE((t + 1) & 1, (t + 1) * 32);                                      \
        asm volatile("s_waitcnt vmcnt(4)" ::: "memory");                       \
        __builtin_amdgcn_s_barrier();                                          \
        COMPUTE(t & 1);                                                        \
        asm volatile("s_waitcnt lgkmcnt(0)" ::: "memory");                     \
        __builtin_amdgcn_s_barrier();                                          \
    }                                                                          \
    asm volatile("s_waitcnt vmcnt(0)" ::: "memory");                           \
    __builtin_amdgcn_s_barrier();                                              \
    COMPUTE(1);

// ---------------------------------------------------------------- QKV GEMM
__global__ __launch_bounds__(256) void k_gemm_qkv(
    const f16* __restrict__ xq, const f16* __restrict__ xk, const f16* __restrict__ xv,
    const f16* __restrict__ wq, const f16* __restrict__ wk, const f16* __restrict__ wv,
    const float* __restrict__ bq, const float* __restrict__ bk, const float* __restrict__ bv,
    f16* __restrict__ Qh, f16* __restrict__ Kh, f16* __restrict__ Vt) {
    __shared__ __align__(16) f16 As[2 * 128 * 32];
    __shared__ __align__(16) f16 Bs[2 * 128 * 32];

    const int t  = blockIdx.y / 6;           // 0:Q 1:K 2:V
    const int n0 = (blockIdx.y % 6) * 128;   // within 768
    const int m0 = blockIdx.x * 128;
    const f16*   X    = (t == 0) ? xq : (t == 1) ? xk : xv;
    const f16*   W    = (t == 0) ? wq : (t == 1) ? wk : wv;
    const float* bias = (t == 0) ? bq : (t == 1) ? bk : bv;

    GEMM_TILE_BODY(X, W)

    // epilogue: C/D layout col=lane&15, row=quad*4+reg
#pragma unroll
    for (int j = 0; j < 4; j++) {
        const int   nj = n0 + wc * 64 + j * 16 + l16;  // 0..767
        const float bb = bias[nj];
        const int   h = nj >> 6, dh = nj & 63;
#pragma unroll
        for (int i = 0; i < 4; i++) {
            const int mb = m0 + wr * 64 + i * 16 + quad * 4;
            const int b = mb >> 10, s = mb & 1023;
            if (t < 2) {
                f16* dst = (t == 0) ? Qh : Kh;
                const int base = ((b * 12 + h) * 1024 + s) * 64 + dh;
#pragma unroll
                for (int r = 0; r < 4; r++)
                    dst[base + r * 64] = (f16)(acc[i][j][r] + bb);
            } else {
                f16x4 pk;
#pragma unroll
                for (int r = 0; r < 4; r++) pk[r] = (f16)(acc[i][j][r] + bb);
                *(f16x4*)(Vt + ((b * 12 + h) * 64 + dh) * 1024 + s) = pk;
            }
        }
    }
}

// ---------------------------------------------------------------- out GEMM
__global__ __launch_bounds__(256) void k_gemm_out(
    const f16* __restrict__ Xin, const f16* __restrict__ Win,
    const float* __restrict__ bias, float* __restrict__ out) {
    __shared__ __align__(16) f16 As[2 * 128 * 32];
    __shared__ __align__(16) f16 Bs[2 * 128 * 32];

    const int n0 = blockIdx.y * 128;
    const int m0 = blockIdx.x * 128;

    GEMM_TILE_BODY(Xin, Win)

#pragma unroll
    for (int j = 0; j < 4; j++) {
        const int   nj = n0 + wc * 64 + j * 16 + l16;
        const float bb = bias[nj];
#pragma unroll
        for (int i = 0; i < 4; i++) {
            const int mb = m0 + wr * 64 + i * 16 + quad * 4;
#pragma unroll
            for (int r = 0; r < 4; r++)
                out[(size_t)(mb + r) * 768 + nj] = acc[i][j][r] + bb;
        }
    }
}

// ---------------------------------------------------------------- fused attention
// One block = (b,h, 16 q-rows). No-max softmax fused into score phase.
// SWAPPED MFMA operands: mfma(Kfrag, Qfrag) -> reg dim = k (4 consecutive),
// lane dim = q. Packed f16x4 sc stores, per-lane scalar row sums (2-shfl
// reduce), band-structured rel lookup (out-of-band = preloaded rLo/rHi).
constexpr int SCP = 1032;  // padded score row stride (f16), 16B-multiple

__global__ __launch_bounds__(256) void k_attn(
    const f16* __restrict__ Qh, const f16* __restrict__ Kh, const f16* __restrict__ Vt,
    const f16* __restrict__ embK, const f16* __restrict__ embVt,
    float* __restrict__ attn, f16* __restrict__ ctx) {
    __shared__ __align__(16) f16 sc[16 * SCP];     // 33,024 B
    __shared__ __align__(16) f16 relw[16 * 160];   //  5,120 B
    __shared__ float red[3][4][16];                // sum,t0,t1 per wave per row
    __shared__ float invs[16], tl0[16], tl1[16];

    const int qt = blockIdx.x, bh = blockIdx.y;
    const int b = bh / 12, h = bh % 12;
    const int q0 = qt * 16;
    const int tid = threadIdx.x;
    const int w = tid >> 6, l = tid & 63, quad = l >> 4, l16 = l & 15;

    const f16* Qb = Qh + (bh * 1024 + q0) * 64;
    const f16* Kb = Kh + bh * 1024 * 64;
    const f16* Vb = Vt + bh * 64 * 1024;

    // B-operand frags of Q: lane l16 = q-row, two k-steps of 32
    const f16x8 qa0 = *(const f16x8*)(Qb + l16 * 64 + quad * 8);
    const f16x8 qa1 = *(const f16x8*)(Qb + l16 * 64 + 32 + quad * 8);

    // phase 0: mfma(embK, Q) -> row(reg)=r-index, col(lane)=q --------
    for (int nf = w; nf < 9; nf += 4) {
        const int r0 = nf * 16;
        int rr = r0 + l16; if (rr > 128) rr = 128;
        const f16x8 eb0 = *(const f16x8*)(embK + rr * 768 + h * 64 + quad * 8);
        const f16x8 eb1 = *(const f16x8*)(embK + rr * 768 + h * 64 + 32 + quad * 8);
        f32x4 a = {};
        a = mfma16(eb0, qa0, a);
        a = mfma16(eb1, qa1, a);
        f16x4 pk;
#pragma unroll
        for (int r = 0; r < 4; r++) pk[r] = (f16)a[r];
        *(f16x4*)(relw + l16 * 160 + r0 + quad * 4) = pk;
    }
    __syncthreads();

    // phase 1: mfma(K, Q) -> row(reg)=k (4 consecutive), col(lane)=q --
    const int qg = q0 + l16;
    const float cLog = 0.18033688f;  // 0.125 * log2(e)
    const float rLo = (float)relw[l16 * 160]       * cLog;  // d <= -64
    const float rHi = (float)relw[l16 * 160 + 128] * cLog;  // d >= +64
    float rs = 0.f, rt0 = 0.f, rt1 = 0.f;
    const int dbase = w * 256 + quad * 4 - qg;
    for (int nf = 0; nf < 16; nf++) {
        const int kc = w * 256 + nf * 16;
        const f16x8 kf0 = *(const f16x8*)(Kb + (kc + l16) * 64 + quad * 8);
        const f16x8 kf1 = *(const f16x8*)(Kb + (kc + l16) * 64 + 32 + quad * 8);
        f32x4 a = {};
        a = mfma16(kf0, qa0, a);
        a = mfma16(kf1, qa1, a);
        const int d0 = dbase + nf * 16;  // d of reg 0; regs are d0..d0+3
        float es[4];
        if (d0 >= 64) {                       // all in upper tail
#pragma unroll
            for (int r = 0; r < 4; r++)
                es[r] = __builtin_amdgcn_exp2f(fmaf(a[r], cLog, rHi));
            const float s4 = (es[0] + es[1]) + (es[2] + es[3]);
            rs += s4; rt1 += s4;
        } else if (d0 <= -67) {               // all in lower tail
#pragma unroll
            for (int r = 0; r < 4; r++)
                es[r] = __builtin_amdgcn_exp2f(fmaf(a[r], cLog, rLo));
            const float s4 = (es[0] + es[1]) + (es[2] + es[3]);
            rs += s4; rt0 += s4;
        } else {                              // band-crossing (rare)
#pragma unroll
            for (int r = 0; r < 4; r++) {
                const int dr = d0 + r;
                const int drc = (dr < -64) ? -64 : (dr > 64) ? 64 : dr;
                const float rv = (float)relw[l16 * 160 + drc + 64] * cLog;
                const float e = __builtin_amdgcn_exp2f(fmaf(a[r], cLog, rv));
                es[r] = e;
                rs += e;
                rt0 += (dr <= -64) ? e : 0.f;
                rt1 += (dr >= 64) ? e : 0.f;
            }
        }
        f16x4 pk;
#pragma unroll
        for (int r = 0; r < 4; r++) pk[r] = (f16)es[r];
        *(f16x4*)(sc + l16 * SCP + kc + quad * 4) = pk;
    }
    // reduce over the 4 quads (lanes sharing l16): xor 16, 32
    rs  += __shfl_xor(rs, 16);  rs  += __shfl_xor(rs, 32);
    rt0 += __shfl_xor(rt0, 16); rt0 += __shfl_xor(rt0, 32);
    rt1 += __shfl_xor(rt1, 16); rt1 += __shfl_xor(rt1, 32);
    if (l < 16) {
        red[0][w][l16] = rs;
        red[1][w][l16] = rt0;
        red[2][w][l16] = rt1;
    }
    __syncthreads();
    if (tid < 16) {
        const float s = red[0][0][tid] + red[0][1][tid] + red[0][2][tid] + red[0][3][tid];
        invs[tid] = 1.f / s;
        tl0[tid] = red[1][0][tid] + red[1][1][tid] + red[1][2][tid] + red[1][3][tid];
        tl1[tid] = red[2][0][tid] + red[2][1][tid] + red[2][2][tid] + red[2][3][tid];
    }
    __syncthreads();

    // phase 3: attn -> global (wave w owns rows 4w..4w+3) ----------
    {
        float* ab = attn + ((long)bh * 1024 + q0) * 1024;
#pragma unroll
        for (int rr = 0; rr < 4; rr++) {
            const int row = w * 4 + rr;
            const float inv = invs[row];
            const f16* p = sc + row * SCP;
            float* o = ab + (long)row * 1024;
#pragma unroll
            for (int jj = 0; jj < 4; jj++) {
                const int c = jj * 256 + l * 4;
                const f16x4 v = *(const f16x4*)(p + c);
                *(float4*)(o + c) = make_float4((float)v[0] * inv, (float)v[1] * inv,
                                                (float)v[2] * inv, (float)v[3] * inv);
            }
        }
    }
    // phase 4: build raw w into relw -------------------------------
    for (int idx = tid; idx < 16 * 160; idx += 256) {
        const int row = idx / 160, r = idx - row * 160;
        float v = 0.f;
        if (r == 0) v = tl0[row];
        else if (r == 128) v = tl1[row];
        else if (r < 128) {
            const int col = q0 + row + r - 64;
            if (col >= 0 && col < 1024) v = (float)sc[row * SCP + col];
        }
        relw[idx] = (f16)v;
    }
    __syncthreads();

    // phase 5: PV + relV (wave w -> dh block w*16) -----------------
    {
        f32x4 a = {};
        const f16* vrow = Vb + (w * 16 + l16) * 1024;
        for (int ks = 0; ks < 32; ks++) {
            const f16x8 af = *(const f16x8*)(sc + l16 * SCP + ks * 32 + quad * 8);
            const f16x8 bf = *(const f16x8*)(vrow + ks * 32 + quad * 8);
            a = mfma16(af, bf, a);
        }
        const f16* erow = embVt + (h * 64 + w * 16 + l16) * 160;
#pragma unroll
        for (int ks = 0; ks < 5; ks++) {
            const f16x8 af = *(const f16x8*)(relw + l16 * 160 + ks * 32 + quad * 8);
            const f16x8 bf = *(const f16x8*)(erow + ks * 32 + quad * 8);
            a = mfma16(af, bf, a);
        }
#pragma unroll
        for (int r = 0; r < 4; r++) {
            const int row = quad * 4 + r;
            const int qg2 = q0 + row;
            ctx[(b * 1024 + qg2) * 768 + h * 64 + w * 16 + l16] = (f16)(a[r] * invs[row]);
        }
    }
}

// ---------------------------------------------------------------- launch
extern "C" void kernel_launch(void* const* d_in, const int* in_sizes, int n_in,
                              void* d_out, int out_size, void* d_ws, size_t ws_size,
                              hipStream_t stream) {
    const float* q_in = (const float*)d_in[0];
    const float* k_in = (const float*)d_in[1];
    const float* v_in = (const float*)d_in[2];
    const float* WQw  = (const float*)d_in[3];
    const float* WQb  = (const float*)d_in[4];
    const float* WKw  = (const float*)d_in[5];
    const float* WKb  = (const float*)d_in[6];
    const float* WVw  = (const float*)d_in[7];
    const float* WVb  = (const float*)d_in[8];
    const float* WOw  = (const float*)d_in[9];
    const float* WOb  = (const float*)d_in[10];
    const float* embK = (const float*)d_in[11];
    const float* embV = (const float*)d_in[12];

    char*  ws  = (char*)d_ws;
    size_t off = 0;
    auto nxt = [&](size_t n) {
        char* p = ws + off;
        off += (n + 255) & ~(size_t)255;
        return p;
    };
    f16* qb    = (f16*)nxt(3145728 * 2);
    f16* kb    = (f16*)nxt(3145728 * 2);
    f16* vb    = (f16*)nxt(3145728 * 2);
    f16* Wqb   = (f16*)nxt(589824 * 2);
    f16* Wkb   = (f16*)nxt(589824 * 2);
    f16* Wvb   = (f16*)nxt(589824 * 2);
    f16* Wob   = (f16*)nxt(589824 * 2);
    f16* embKb = (f16*)nxt(99072 * 2);
    f16* embVt = (f16*)nxt(122880 * 2);
    f16* Qh    = (f16*)nxt(3145728 * 2);
    f16* Kh    = (f16*)nxt(3145728 * 2);
    f16* Vt    = (f16*)nxt(3145728 * 2);
    f16* ctx   = (f16*)nxt(3145728 * 2);
    (void)ws_size; (void)in_sizes; (void)n_in; (void)out_size;

    ConvArgs ca;
    ca.src[0] = q_in; ca.src[1] = k_in; ca.src[2] = v_in;
    ca.src[3] = WQw;  ca.src[4] = WKw;  ca.src[5] = WVw;
    ca.src[6] = WOw;  ca.src[7] = embK;
    ca.dst[0] = qb;   ca.dst[1] = kb;   ca.dst[2] = vb;
    ca.dst[3] = Wqb;  ca.dst[4] = Wkb;  ca.dst[5] = Wvb;
    ca.dst[6] = Wob;  ca.dst[7] = embKb;

    k_convert<<<dim3(2048 + 480), dim3(256), 0, stream>>>(ca, embV, embVt);
    k_gemm_qkv<<<dim3(32, 18), dim3(256), 0, stream>>>(
        qb, kb, vb, Wqb, Wkb, Wvb, WQb, WKb, WVb, Qh, Kh, Vt);
    float* attn = (float*)d_out + 3145728;
    k_attn<<<dim3(64, 48), dim3(256), 0, stream>>>(Qh, Kh, Vt, embKb, embVt, attn, ctx);
    k_gemm_out<<<dim3(32, 6), dim3(256), 0, stream>>>(ctx, Wob, WOb, (float*)d_out);
}

// Round 3
// 392.835 us; speedup vs baseline: 1.0195x; 1.0195x over previous
//
#include <hip/hip_runtime.h>

typedef _Float16 f16;
typedef _Float16 f16x4 __attribute__((ext_vector_type(4)));
typedef _Float16 f16x8 __attribute__((ext_vector_type(8)));
typedef float    f32x4 __attribute__((ext_vector_type(4)));

#define DEV static __device__ __forceinline__

DEV f32x4 mfma16(f16x8 a, f16x8 b, f32x4 c) {
    return __builtin_amdgcn_mfma_f32_16x16x32_f16(a, b, c, 0, 0, 0);
}

// async global->LDS, 16B per lane, dest = wave-uniform base + lane*16
DEV void gload16(const f16* g, f16* l) {
    __builtin_amdgcn_global_load_lds(
        (const __attribute__((address_space(1))) unsigned int*)g,
        (__attribute__((address_space(3))) unsigned int*)l,
        16, 0, 0);
}

// ---------------------------------------------------------------- constants
// B=4, S=1024, D=768, H=12, DH=64, R=129 (padded to 160 for k-steps of 32)

// ---------------------------------------------------------------- convert
// Rewritten round 3: blockIdx.y selects the tensor (wave-uniform switch on
// SGPR -> pointers stay in SGPRs). The old version runtime-indexed a local
// seg[9] table AND ConvArgs.src[s]/dst[s] kernarg arrays with a per-lane
// value -> scratch spills on every element (rule #20). No tables now.
__global__ __launch_bounds__(256) void k_convert(
    const float* __restrict__ q_in, const float* __restrict__ k_in,
    const float* __restrict__ v_in, const float* __restrict__ wq,
    const float* __restrict__ wk, const float* __restrict__ wv,
    const float* __restrict__ wo, const float* __restrict__ embK,
    const float* __restrict__ embV,
    f16* __restrict__ qb, f16* __restrict__ kb, f16* __restrict__ vb,
    f16* __restrict__ wqb, f16* __restrict__ wkb, f16* __restrict__ wvb,
    f16* __restrict__ wob, f16* __restrict__ embKb, f16* __restrict__ embVt) {
    const int y = blockIdx.y;
    const int tid0 = blockIdx.x * 256 + threadIdx.x;  // 0..131071
    if (y == 8) {  // embVt[h][dh][r] transpose+pad: 12*64*160 = 122880
        if (tid0 < 122880) {
            const int r  = tid0 % 160;
            const int dh = (tid0 / 160) & 63;
            const int h  = tid0 / (160 * 64);
            float v = 0.f;
            if (r < 129) v = embV[r * 768 + h * 64 + dh];
            embVt[tid0] = (f16)v;
        }
        return;
    }
    const float* src;
    f16*         dst;
    int          n;  // in float4 units
    switch (y) {
        case 0: src = q_in; dst = qb;    n = 786432; break;
        case 1: src = k_in; dst = kb;    n = 786432; break;
        case 2: src = v_in; dst = vb;    n = 786432; break;
        case 3: src = wq;   dst = wqb;   n = 147456; break;
        case 4: src = wk;   dst = wkb;   n = 147456; break;
        case 5: src = wv;   dst = wvb;   n = 147456; break;
        case 6: src = wo;   dst = wob;   n = 147456; break;
        default: src = embK; dst = embKb; n = 24768; break;
    }
    for (int j = tid0; j < n; j += 512 * 256) {
        const float4 v = ((const float4*)src)[j];
        f16x4 o;
        o[0] = (f16)v.x; o[1] = (f16)v.y; o[2] = (f16)v.z; o[3] = (f16)v.w;
        ((f16x4*)dst)[j] = o;
    }
}

// ---------------------------------------------------------------- GEMM core
// 128x128 tile, BK=32, DOUBLE-BUFFERED 2-phase pipeline (T3-minimum):
// issue STAGE(next) before computing current; counted s_waitcnt vmcnt(4)
// + raw s_barrier. lgkmcnt(0)+barrier after compute protects the buffer
// the next STAGE overwrites. XOR chunk swizzle: slot (r,c) holds global
// chunk c^s(r), s(r)=((r)^(r>>2))&3.
#define GEMM_TILE_BODY(X, W)                                                   \
    const int tid = threadIdx.x;                                               \
    const int w = tid >> 6, l = tid & 63, quad = l >> 4, l16 = l & 15;         \
    const int wr = w >> 1, wc = w & 1;                                         \
    const int rl = l >> 2, cc = l & 3;                                         \
    const int csrc = (cc ^ ((rl ^ (rl >> 2)) & 3)) * 8;                        \
    const f16* gA = (X) + (size_t)(m0 + w * 32 + rl) * 768 + csrc;             \
    const f16* gB = (W) + (size_t)(n0 + w * 32 + rl) * 768 + csrc;             \
    const int xsw = (quad ^ ((l16 ^ (l16 >> 2)) & 3)) * 8;                     \
    f32x4 acc[4][4] = {};                                                      \
    auto STAGE = [&](int pp, int kk) {                                         \
        f16* lA = As + pp * 4096 + (w * 32) * 32;                              \
        f16* lB = Bs + pp * 4096 + (w * 32) * 32;                              \
        gload16(gA + kk, lA);                                                  \
        gload16(gA + kk + 16 * 768, lA + 16 * 32);                             \
        gload16(gB + kk, lB);                                                  \
        gload16(gB + kk + 16 * 768, lB + 16 * 32);                             \
    };                                                                         \
    auto COMPUTE = [&](int pp) {                                               \
        const f16* Ab = As + pp * 4096;                                        \
        const f16* Bb = Bs + pp * 4096;                                        \
        f16x8 af[4], bf[4];                                                    \
        _Pragma("unroll") for (int i = 0; i < 4; i++)                          \
            af[i] = *(const f16x8*)(Ab + (wr * 64 + i * 16 + l16) * 32 + xsw); \
        _Pragma("unroll") for (int i = 0; i < 4; i++)                          \
            bf[i] = *(const f16x8*)(Bb + (wc * 64 + i * 16 + l16) * 32 + xsw); \
        _Pragma("unroll") for (int i = 0; i < 4; i++)                          \
            _Pragma("unroll") for (int j = 0; j < 4; j++)                      \
                acc[i][j] = mfma16(af[i], bf[j], acc[i][j]);                   \
    };                                                                         \
    STAGE(0, 0);                                                               \
    _Pragma("unroll 1") for (int t = 0; t < 23; ++t) {                         \
        STAGE((t + 1) & 1, (t + 1) * 32);                                      \
        asm volatile("s_waitcnt vmcnt(4)" ::: "memory");                       \
        __builtin_amdgcn_s_barrier();                                          \
        COMPUTE(t & 1);                                                        \
        asm volatile("s_waitcnt lgkmcnt(0)" ::: "memory");                     \
        __builtin_amdgcn_s_barrier();                                          \
    }                                                                          \
    asm volatile("s_waitcnt vmcnt(0)" ::: "memory");                           \
    __builtin_amdgcn_s_barrier();                                              \
    COMPUTE(1);

// ---------------------------------------------------------------- QKV GEMM
__global__ __launch_bounds__(256) void k_gemm_qkv(
    const f16* __restrict__ xq, const f16* __restrict__ xk, const f16* __restrict__ xv,
    const f16* __restrict__ wq, const f16* __restrict__ wk, const f16* __restrict__ wv,
    const float* __restrict__ bq, const float* __restrict__ bk, const float* __restrict__ bv,
    f16* __restrict__ Qh, f16* __restrict__ Kh, f16* __restrict__ Vt) {
    __shared__ __align__(16) f16 As[2 * 128 * 32];
    __shared__ __align__(16) f16 Bs[2 * 128 * 32];

    const int t  = blockIdx.y / 6;           // 0:Q 1:K 2:V
    const int n0 = (blockIdx.y % 6) * 128;   // within 768
    const int m0 = blockIdx.x * 128;
    const f16*   X    = (t == 0) ? xq : (t == 1) ? xk : xv;
    const f16*   W    = (t == 0) ? wq : (t == 1) ? wk : wv;
    const float* bias = (t == 0) ? bq : (t == 1) ? bk : bv;

    GEMM_TILE_BODY(X, W)

    // epilogue: C/D layout col=lane&15, row=quad*4+reg
#pragma unroll
    for (int j = 0; j < 4; j++) {
        const int   nj = n0 + wc * 64 + j * 16 + l16;  // 0..767
        const float bb = bias[nj];
        const int   h = nj >> 6, dh = nj & 63;
#pragma unroll
        for (int i = 0; i < 4; i++) {
            const int mb = m0 + wr * 64 + i * 16 + quad * 4;
            const int b = mb >> 10, s = mb & 1023;
            if (t < 2) {
                f16* dst = (t == 0) ? Qh : Kh;
                const int base = ((b * 12 + h) * 1024 + s) * 64 + dh;
#pragma unroll
                for (int r = 0; r < 4; r++)
                    dst[base + r * 64] = (f16)(acc[i][j][r] + bb);
            } else {
                f16x4 pk;
#pragma unroll
                for (int r = 0; r < 4; r++) pk[r] = (f16)(acc[i][j][r] + bb);
                *(f16x4*)(Vt + ((b * 12 + h) * 64 + dh) * 1024 + s) = pk;
            }
        }
    }
}

// ---------------------------------------------------------------- out GEMM
// Round 3: 64x64 tiles -> 768 blocks (3/CU vs 192 blocks = 0.75/CU). The
// 2-phase pipeline cannot hide latency with <1 resident block per CU.
__global__ __launch_bounds__(256) void k_gemm_out(
    const f16* __restrict__ Xin, const f16* __restrict__ Win,
    const float* __restrict__ bias, float* __restrict__ out) {
    __shared__ __align__(16) f16 As[2 * 64 * 32];
    __shared__ __align__(16) f16 Bs[2 * 64 * 32];

    const int n0 = blockIdx.y * 64;
    const int m0 = blockIdx.x * 64;
    const int tid = threadIdx.x;
    const int w = tid >> 6, l = tid & 63, quad = l >> 4, l16 = l & 15;
    const int wr = w >> 1, wc = w & 1;
    const int rl = l >> 2, cc = l & 3;
    const int csrc = (cc ^ ((rl ^ (rl >> 2)) & 3)) * 8;
    const f16* gA = Xin + (size_t)(m0 + w * 16 + rl) * 768 + csrc;
    const f16* gB = Win + (size_t)(n0 + w * 16 + rl) * 768 + csrc;
    const int xsw = (quad ^ ((l16 ^ (l16 >> 2)) & 3)) * 8;
    f32x4 acc[2][2] = {};
    auto STAGE = [&](int pp, int kk) {
        gload16(gA + kk, As + pp * 2048 + (w * 16) * 32);
        gload16(gB + kk, Bs + pp * 2048 + (w * 16) * 32);
    };
    auto COMPUTE = [&](int pp) {
        const f16* Ab = As + pp * 2048;
        const f16* Bb = Bs + pp * 2048;
        f16x8 af[2], bf[2];
#pragma unroll
        for (int i = 0; i < 2; i++)
            af[i] = *(const f16x8*)(Ab + (wr * 32 + i * 16 + l16) * 32 + xsw);
#pragma unroll
        for (int j = 0; j < 2; j++)
            bf[j] = *(const f16x8*)(Bb + (wc * 32 + j * 16 + l16) * 32 + xsw);
#pragma unroll
        for (int i = 0; i < 2; i++)
#pragma unroll
            for (int j = 0; j < 2; j++)
                acc[i][j] = mfma16(af[i], bf[j], acc[i][j]);
    };
    STAGE(0, 0);
#pragma unroll 1
    for (int t = 0; t < 23; ++t) {
        STAGE((t + 1) & 1, (t + 1) * 32);
        asm volatile("s_waitcnt vmcnt(2)" ::: "memory");
        __builtin_amdgcn_s_barrier();
        COMPUTE(t & 1);
        asm volatile("s_waitcnt lgkmcnt(0)" ::: "memory");
        __builtin_amdgcn_s_barrier();
    }
    asm volatile("s_waitcnt vmcnt(0)" ::: "memory");
    __builtin_amdgcn_s_barrier();
    COMPUTE(1);

#pragma unroll
    for (int j = 0; j < 2; j++) {
        const int   nj = n0 + wc * 32 + j * 16 + l16;
        const float bb = bias[nj];
#pragma unroll
        for (int i = 0; i < 2; i++) {
            const int mb = m0 + wr * 32 + i * 16 + quad * 4;
#pragma unroll
            for (int r = 0; r < 4; r++)
                out[(size_t)(mb + r) * 768 + nj] = acc[i][j][r] + bb;
        }
    }
}

// ---------------------------------------------------------------- fused attention
// One block = (b,h, 16 q-rows). No-max softmax fused into score phase.
// SWAPPED MFMA operands: mfma(Kfrag, Qfrag) -> reg dim = k (4 consecutive),
// lane dim = q. Packed f16x4 sc stores, per-lane scalar row sums (2-shfl
// reduce), band-structured rel lookup (out-of-band = preloaded rLo/rHi).
constexpr int SCP = 1032;  // padded score row stride (f16), 16B-multiple

__global__ __launch_bounds__(256) void k_attn(
    const f16* __restrict__ Qh, const f16* __restrict__ Kh, const f16* __restrict__ Vt,
    const f16* __restrict__ embK, const f16* __restrict__ embVt,
    float* __restrict__ attn, f16* __restrict__ ctx) {
    __shared__ __align__(16) f16 sc[16 * SCP];     // 33,024 B
    __shared__ __align__(16) f16 relw[16 * 160];   //  5,120 B
    __shared__ float red[3][4][16];                // sum,t0,t1 per wave per row
    __shared__ float invs[16], tl0[16], tl1[16];

    const int qt = blockIdx.x, bh = blockIdx.y;
    const int b = bh / 12, h = bh % 12;
    const int q0 = qt * 16;
    const int tid = threadIdx.x;
    const int w = tid >> 6, l = tid & 63, quad = l >> 4, l16 = l & 15;

    const f16* Qb = Qh + (bh * 1024 + q0) * 64;
    const f16* Kb = Kh + bh * 1024 * 64;
    const f16* Vb = Vt + bh * 64 * 1024;

    // B-operand frags of Q: lane l16 = q-row, two k-steps of 32
    const f16x8 qa0 = *(const f16x8*)(Qb + l16 * 64 + quad * 8);
    const f16x8 qa1 = *(const f16x8*)(Qb + l16 * 64 + 32 + quad * 8);

    // phase 0: mfma(embK, Q) -> row(reg)=r-index, col(lane)=q --------
    for (int nf = w; nf < 9; nf += 4) {
        const int r0 = nf * 16;
        int rr = r0 + l16; if (rr > 128) rr = 128;
        const f16x8 eb0 = *(const f16x8*)(embK + rr * 768 + h * 64 + quad * 8);
        const f16x8 eb1 = *(const f16x8*)(embK + rr * 768 + h * 64 + 32 + quad * 8);
        f32x4 a = {};
        a = mfma16(eb0, qa0, a);
        a = mfma16(eb1, qa1, a);
        f16x4 pk;
#pragma unroll
        for (int r = 0; r < 4; r++) pk[r] = (f16)a[r];
        *(f16x4*)(relw + l16 * 160 + r0 + quad * 4) = pk;
    }
    __syncthreads();

    // phase 1: mfma(K, Q) -> row(reg)=k (4 consecutive), col(lane)=q --
    const int qg = q0 + l16;
    const float cLog = 0.18033688f;  // 0.125 * log2(e)
    const float rLo = (float)relw[l16 * 160]       * cLog;  // d <= -64
    const float rHi = (float)relw[l16 * 160 + 128] * cLog;  // d >= +64
    float rs = 0.f, rt0 = 0.f, rt1 = 0.f;
    const int dbase = w * 256 + quad * 4 - qg;
    for (int nf = 0; nf < 16; nf++) {
        const int kc = w * 256 + nf * 16;
        const f16x8 kf0 = *(const f16x8*)(Kb + (kc + l16) * 64 + quad * 8);
        const f16x8 kf1 = *(const f16x8*)(Kb + (kc + l16) * 64 + 32 + quad * 8);
        f32x4 a = {};
        a = mfma16(kf0, qa0, a);
        a = mfma16(kf1, qa1, a);
        const int d0 = dbase + nf * 16;  // d of reg 0; regs are d0..d0+3
        float es[4];
        if (d0 >= 64) {                       // all in upper tail
#pragma unroll
            for (int r = 0; r < 4; r++)
                es[r] = __builtin_amdgcn_exp2f(fmaf(a[r], cLog, rHi));
            const float s4 = (es[0] + es[1]) + (es[2] + es[3]);
            rs += s4; rt1 += s4;
        } else if (d0 <= -67) {               // all in lower tail
#pragma unroll
            for (int r = 0; r < 4; r++)
                es[r] = __builtin_amdgcn_exp2f(fmaf(a[r], cLog, rLo));
            const float s4 = (es[0] + es[1]) + (es[2] + es[3]);
            rs += s4; rt0 += s4;
        } else {                              // band-crossing (rare)
#pragma unroll
            for (int r = 0; r < 4; r++) {
                const int dr = d0 + r;
                const int drc = (dr < -64) ? -64 : (dr > 64) ? 64 : dr;
                const float rv = (float)relw[l16 * 160 + drc + 64] * cLog;
                const float e = __builtin_amdgcn_exp2f(fmaf(a[r], cLog, rv));
                es[r] = e;
                rs += e;
                rt0 += (dr <= -64) ? e : 0.f;
                rt1 += (dr >= 64) ? e : 0.f;
            }
        }
        f16x4 pk;
#pragma unroll
        for (int r = 0; r < 4; r++) pk[r] = (f16)es[r];
        *(f16x4*)(sc + l16 * SCP + kc + quad * 4) = pk;
    }
    // reduce over the 4 quads (lanes sharing l16): xor 16, 32
    rs  += __shfl_xor(rs, 16);  rs  += __shfl_xor(rs, 32);
    rt0 += __shfl_xor(rt0, 16); rt0 += __shfl_xor(rt0, 32);
    rt1 += __shfl_xor(rt1, 16); rt1 += __shfl_xor(rt1, 32);
    if (l < 16) {
        red[0][w][l16] = rs;
        red[1][w][l16] = rt0;
        red[2][w][l16] = rt1;
    }
    __syncthreads();
    if (tid < 16) {
        const float s = red[0][0][tid] + red[0][1][tid] + red[0][2][tid] + red[0][3][tid];
        invs[tid] = 1.f / s;
        tl0[tid] = red[1][0][tid] + red[1][1][tid] + red[1][2][tid] + red[1][3][tid];
        tl1[tid] = red[2][0][tid] + red[2][1][tid] + red[2][2][tid] + red[2][3][tid];
    }
    __syncthreads();

    // phase 3: attn -> global (wave w owns rows 4w..4w+3) ----------
    {
        float* ab = attn + ((long)bh * 1024 + q0) * 1024;
#pragma unroll
        for (int rr = 0; rr < 4; rr++) {
            const int row = w * 4 + rr;
            const float inv = invs[row];
            const f16* p = sc + row * SCP;
            float* o = ab + (long)row * 1024;
#pragma unroll
            for (int jj = 0; jj < 4; jj++) {
                const int c = jj * 256 + l * 4;
                const f16x4 v = *(const f16x4*)(p + c);
                *(float4*)(o + c) = make_float4((float)v[0] * inv, (float)v[1] * inv,
                                                (float)v[2] * inv, (float)v[3] * inv);
            }
        }
    }
    // phase 4: build raw w into relw -------------------------------
    for (int idx = tid; idx < 16 * 160; idx += 256) {
        const int row = idx / 160, r = idx - row * 160;
        float v = 0.f;
        if (r == 0) v = tl0[row];
        else if (r == 128) v = tl1[row];
        else if (r < 128) {
            const int col = q0 + row + r - 64;
            if (col >= 0 && col < 1024) v = (float)sc[row * SCP + col];
        }
        relw[idx] = (f16)v;
    }
    __syncthreads();

    // phase 5: PV + relV (wave w -> dh block w*16) -----------------
    {
        f32x4 a = {};
        const f16* vrow = Vb + (w * 16 + l16) * 1024;
        for (int ks = 0; ks < 32; ks++) {
            const f16x8 af = *(const f16x8*)(sc + l16 * SCP + ks * 32 + quad * 8);
            const f16x8 bf = *(const f16x8*)(vrow + ks * 32 + quad * 8);
            a = mfma16(af, bf, a);
        }
        const f16* erow = embVt + (h * 64 + w * 16 + l16) * 160;
#pragma unroll
        for (int ks = 0; ks < 5; ks++) {
            const f16x8 af = *(const f16x8*)(relw + l16 * 160 + ks * 32 + quad * 8);
            const f16x8 bf = *(const f16x8*)(erow + ks * 32 + quad * 8);
            a = mfma16(af, bf, a);
        }
#pragma unroll
        for (int r = 0; r < 4; r++) {
            const int row = quad * 4 + r;
            const int qg2 = q0 + row;
            ctx[(b * 1024 + qg2) * 768 + h * 64 + w * 16 + l16] = (f16)(a[r] * invs[row]);
        }
    }
}

// ---------------------------------------------------------------- launch
extern "C" void kernel_launch(void* const* d_in, const int* in_sizes, int n_in,
                              void* d_out, int out_size, void* d_ws, size_t ws_size,
                              hipStream_t stream) {
    const float* q_in = (const float*)d_in[0];
    const float* k_in = (const float*)d_in[1];
    const float* v_in = (const float*)d_in[2];
    const float* WQw  = (const float*)d_in[3];
    const float* WQb  = (const float*)d_in[4];
    const float* WKw  = (const float*)d_in[5];
    const float* WKb  = (const float*)d_in[6];
    const float* WVw  = (const float*)d_in[7];
    const float* WVb  = (const float*)d_in[8];
    const float* WOw  = (const float*)d_in[9];
    const float* WOb  = (const float*)d_in[10];
    const float* embK = (const float*)d_in[11];
    const float* embV = (const float*)d_in[12];

    char*  ws  = (char*)d_ws;
    size_t off = 0;
    auto nxt = [&](size_t n) {
        char* p = ws + off;
        off += (n + 255) & ~(size_t)255;
        return p;
    };
    f16* qb    = (f16*)nxt(3145728 * 2);
    f16* kb    = (f16*)nxt(3145728 * 2);
    f16* vb    = (f16*)nxt(3145728 * 2);
    f16* Wqb   = (f16*)nxt(589824 * 2);
    f16* Wkb   = (f16*)nxt(589824 * 2);
    f16* Wvb   = (f16*)nxt(589824 * 2);
    f16* Wob   = (f16*)nxt(589824 * 2);
    f16* embKb = (f16*)nxt(99072 * 2);
    f16* embVt = (f16*)nxt(122880 * 2);
    f16* Qh    = (f16*)nxt(3145728 * 2);
    f16* Kh    = (f16*)nxt(3145728 * 2);
    f16* Vt    = (f16*)nxt(3145728 * 2);
    f16* ctx   = (f16*)nxt(3145728 * 2);
    (void)ws_size; (void)in_sizes; (void)n_in; (void)out_size;

    k_convert<<<dim3(512, 9), dim3(256), 0, stream>>>(
        q_in, k_in, v_in, WQw, WKw, WVw, WOw, embK, embV,
        qb, kb, vb, Wqb, Wkb, Wvb, Wob, embKb, embVt);
    k_gemm_qkv<<<dim3(32, 18), dim3(256), 0, stream>>>(
        qb, kb, vb, Wqb, Wkb, Wvb, WQb, WKb, WVb, Qh, Kh, Vt);
    float* attn = (float*)d_out + 3145728;
    k_attn<<<dim3(64, 48), dim3(256), 0, stream>>>(Qh, Kh, Vt, embKb, embVt, attn, ctx);
    k_gemm_out<<<dim3(64, 12), dim3(256), 0, stream>>>(ctx, Wob, WOb, (float*)d_out);
}